// Round 12
// baseline (307.669 us; speedup 1.0000x reference)
//
#include <hip/hip_runtime.h>
#include <math.h>

#define D_    2048
#define QH_   32
#define KVH_  8
#define HD_   64
#define B_    2
#define S_    2048
#define NROW_ (B_*S_)     // 4096
#define KVD_  (KVH_*HD_)  // 512
#define LOG2E 1.44269504f

typedef __bf16 bf16;
typedef __bf16 bf16x2 __attribute__((ext_vector_type(2)));
typedef __bf16 bf16x4 __attribute__((ext_vector_type(4)));
typedef __bf16 bf16x8 __attribute__((ext_vector_type(8)));
typedef float  f32x4  __attribute__((ext_vector_type(4)));
typedef float  f32x16 __attribute__((ext_vector_type(16)));

__device__ __forceinline__ f32x4 mfma16(bf16x8 a, bf16x8 b, f32x4 c) {
  return __builtin_amdgcn_mfma_f32_16x16x32_bf16(a, b, c, 0, 0, 0);
}
__device__ __forceinline__ f32x16 mfma32(bf16x8 a, bf16x8 b, f32x16 c) {
  return __builtin_amdgcn_mfma_f32_32x32x16_bf16(a, b, c, 0, 0, 0);
}

__device__ __forceinline__ void gload_lds16(const bf16* g, bf16* l) {
  __builtin_amdgcn_global_load_lds(
      (const __attribute__((address_space(1))) void*)g,
      (__attribute__((address_space(3))) void*)l, 16, 0, 0);
}

__device__ __forceinline__ unsigned pack_bf16(float a, float b) {
  union { bf16x2 v; unsigned u; } t;
  t.v[0] = (bf16)a; t.v[1] = (bf16)b;
  return t.u;
}

// ---------------- RoPE cos/sin table: tab[s*32+d] = {cos, sin} ----------------
__global__ void k_ropetab(float2* __restrict__ tab) {
  int idx = blockIdx.x * 256 + threadIdx.x;   // S_*32 = 65536
  int s = idx >> 5, d = idx & 31;
  float invf = exp2f(-(float)d * 0.62286151f);   // theta^(-d/32), log2(1e6)/32
  float ang = (float)s * invf;
  float sn, cs;
  sincosf(ang, &sn, &cs);
  tab[idx] = make_float2(cs, sn);
}

// ---------------- fp32 -> bf16 converts ----------------
__global__ void k_convert(const float* __restrict__ in, bf16* __restrict__ out, int n4) {
  int i = blockIdx.x * 256 + threadIdx.x;
  if (i >= n4) return;
  f32x4 v = ((const f32x4*)in)[i];
  bf16x4 o;
#pragma unroll
  for (int j = 0; j < 4; j++) o[j] = (bf16)v[j];
  ((bf16x4*)out)[i] = o;
}

__global__ void k_convert2(const float* __restrict__ in0, const float* __restrict__ in1,
                           bf16* __restrict__ o0, bf16* __restrict__ o1, int n4) {
  const float* in = blockIdx.z ? in1 : in0;
  bf16* out = blockIdx.z ? o1 : o0;
  int i = blockIdx.x * 256 + threadIdx.x;
  if (i >= n4) return;
  f32x4 v = ((const f32x4*)in)[i];
  bf16x4 o;
#pragma unroll
  for (int j = 0; j < 4; j++) o[j] = (bf16)v[j];
  ((bf16x4*)out)[i] = o;
}

// ---------- transpose-convert W[K][N] f32 -> Wt[N][K] bf16 ----------
__device__ __forceinline__ void transpose_w_body(const float* W, bf16* Wt, int K, int N) {
  __shared__ float tile[32][33];
  int n0 = blockIdx.x * 32, k0 = blockIdx.y * 32;
  int tx = threadIdx.x, ty = threadIdx.y;  // (32,8)
#pragma unroll
  for (int j = 0; j < 4; j++)
    tile[ty + 8*j][tx] = W[(size_t)(k0 + ty + 8*j) * N + n0 + tx];
  __syncthreads();
#pragma unroll
  for (int j = 0; j < 4; j++)
    Wt[(size_t)(n0 + ty + 8*j) * K + k0 + tx] = (bf16)tile[tx][ty + 8*j];
}

__global__ void k_transpose_w(const float* __restrict__ W, bf16* __restrict__ Wt,
                              int K, int N) {
  transpose_w_body(W, Wt, K, N);
}

__global__ void k_transpose_w2(const float* __restrict__ W0, const float* __restrict__ W1,
                               bf16* __restrict__ T0, bf16* __restrict__ T1) {
  transpose_w_body(blockIdx.z ? W1 : W0, blockIdx.z ? T1 : T0, D_, KVD_);
}

// ---------- Big GEMM: BM=128, BN=256, 4 waves (2M x 2N), wave tile 64x128 ----
// BK=64 double-buffered, 8-chunk XOR swizzle. Grid (N/256, M/128) = 256 blocks.
// Chunk counts (16B): A tile 128x64 = 1024 -> 4/thr; B tile 256x64 = 2048 -> 8/thr.
// (r10 bug: B at 4/thr -> NaN; r11 bug: A at 2/thr -> absmax 3.6.)
// EPI: 1 = RoPE bf16 out (wave's 128 cols = 2 heads)   2 = +bias fp32 out
template<int EPI>
__device__ __forceinline__ void gemm_big(const bf16* A, const bf16* Bt, void* Cout,
                                         const float* bias, const float2* tab,
                                         int M, int N, int K) {
  __shared__ alignas(16) bf16 As[2][128 * 64];
  __shared__ alignas(16) bf16 Bs[2][256 * 64];
  int tid = threadIdx.x;
  int wave = tid >> 6, lane = tid & 63, hi = lane >> 4, lr = lane & 15;
  int wm = wave >> 1, wn = wave & 1;
  int m0 = blockIdx.y * 128, n0 = blockIdx.x * 256;
  f32x4 acc[4][8] = {};
  int nk = K >> 6;   // BK=64

  int a_row[4], a_dch[4], b_row[8], b_dch[8];
#pragma unroll
  for (int i = 0; i < 4; i++) {
    int c = i * 256 + tid;
    a_row[i] = c >> 3;
    a_dch[i] = (c & 7) ^ (a_row[i] & 7);
  }
#pragma unroll
  for (int i = 0; i < 8; i++) {
    int c = i * 256 + tid;
    b_row[i] = c >> 3;
    b_dch[i] = (c & 7) ^ (b_row[i] & 7);
  }

#define GSTAGEB(buf, kt_)                                                      \
  do {                                                                         \
    int k0_ = (kt_) * 64;                                                      \
    _Pragma("unroll")                                                          \
    for (int i = 0; i < 4; i++)                                                \
      gload_lds16(A + (size_t)(m0 + a_row[i]) * K + k0_ + a_dch[i] * 8,        \
                  &As[buf][(i * 256 + wave * 64) * 8]);                        \
    _Pragma("unroll")                                                          \
    for (int i = 0; i < 8; i++)                                                \
      gload_lds16(Bt + (size_t)(n0 + b_row[i]) * K + k0_ + b_dch[i] * 8,       \
                  &Bs[buf][(i * 256 + wave * 64) * 8]);                        \
  } while (0)

  GSTAGEB(0, 0);
  __syncthreads();

  for (int kt = 0; kt < nk; kt++) {
    int cur = kt & 1;
    if (kt + 1 < nk) GSTAGEB(cur ^ 1, kt + 1);   // in flight across compute
#pragma unroll
    for (int kk = 0; kk < 2; kk++) {
      bf16x8 af[4], bfr[8];
#pragma unroll
      for (int mt = 0; mt < 4; mt++) {
        int row = wm * 64 + mt * 16 + lr;
        int sl = (kk * 4 + hi) ^ (row & 7);
        af[mt] = *(const bf16x8*)(&As[cur][row * 64 + sl * 8]);
      }
#pragma unroll
      for (int nt = 0; nt < 8; nt++) {
        int row = wn * 128 + nt * 16 + lr;
        int sl = (kk * 4 + hi) ^ (row & 7);
        bfr[nt] = *(const bf16x8*)(&Bs[cur][row * 64 + sl * 8]);
      }
      __builtin_amdgcn_s_setprio(1);
#pragma unroll
      for (int mt = 0; mt < 4; mt++)
#pragma unroll
        for (int nt = 0; nt < 8; nt++)
          acc[mt][nt] = mfma16(af[mt], bfr[nt], acc[mt][nt]);
      __builtin_amdgcn_s_setprio(0);
    }
    __syncthreads();   // drains prefetch + protects buffer swap
  }
#undef GSTAGEB

  if (EPI == 1) {
    // wave cols [n0+wn*128, +128) = 2 heads of 64; pair (d,d+32) = frag (nt,nt+2)
#pragma unroll
    for (int mt = 0; mt < 4; mt++)
#pragma unroll
      for (int r = 0; r < 4; r++) {
        int grow = m0 + wm * 64 + mt * 16 + 4 * hi + r;
        int s = grow & (S_ - 1);
#pragma unroll
        for (int g2 = 0; g2 < 8; g2 += 4)
#pragma unroll
          for (int j = 0; j < 2; j++) {
            int nt = g2 + j;
            int gcol = n0 + wn * 128 + nt * 16 + lr;
            float2 cs = tab[s * 32 + j * 16 + lr];
            float x1 = acc[mt][nt][r], x2 = acc[mt][nt + 2][r];
            ((bf16*)Cout)[(size_t)grow * N + gcol]      = (bf16)(x1 * cs.x - x2 * cs.y);
            ((bf16*)Cout)[(size_t)grow * N + gcol + 32] = (bf16)(x2 * cs.x + x1 * cs.y);
          }
      }
  } else {
#pragma unroll
    for (int mt = 0; mt < 4; mt++)
#pragma unroll
      for (int nt = 0; nt < 8; nt++)
#pragma unroll
        for (int r = 0; r < 4; r++) {
          int grow = m0 + wm * 64 + mt * 16 + 4 * hi + r;
          int gcol = n0 + wn * 128 + nt * 16 + lr;
          ((float*)Cout)[(size_t)grow * N + gcol] = acc[mt][nt][r] + bias[gcol];
        }
  }
}

__global__ __launch_bounds__(256) void k_gemm_q(const bf16* __restrict__ A,
                                                const bf16* __restrict__ Bt,
                                                bf16* __restrict__ C,
                                                const float2* __restrict__ tab) {
  gemm_big<1>(A, Bt, C, nullptr, tab, NROW_, D_, D_);
}

__global__ __launch_bounds__(256) void k_gemm_o(const bf16* __restrict__ A,
                                                const bf16* __restrict__ Bt,
                                                float* __restrict__ C,
                                                const float* __restrict__ bias) {
  gemm_big<2>(A, Bt, C, bias, nullptr, NROW_, D_, D_);
}

// ---------------- KV GEMM: 64x128 tile, full-chip (512 blocks) ---------------
// EPI: 1 = RoPE K out   3 = transposed V store (swapped mfma operands)
template<int EPI>
__device__ __forceinline__ void gemm_body64(bf16* Asb, bf16* Bsb,
                                            const bf16* A, const bf16* Bt, void* Cout,
                                            const float2* tab) {
  const int K = D_, N = KVD_;
  int tid = threadIdx.x;
  int wave = tid >> 6, lane = tid & 63, hi = lane >> 4, lr = lane & 15;
  int m0 = blockIdx.y * 64, n0 = blockIdx.x * 128;
  int nbase = (wave >> 1) * 64 + (wave & 1) * 16;   // + nt*32
  f32x4 acc[4][2] = {};
  const int nk = K >> 6;

  int a_row[2], a_dch[2], b_row[4], b_dch[4];
#pragma unroll
  for (int i = 0; i < 2; i++) {
    int c = i * 256 + tid;
    a_row[i] = c >> 3;
    a_dch[i] = (c & 7) ^ (a_row[i] & 7);
  }
#pragma unroll
  for (int i = 0; i < 4; i++) {
    int c = i * 256 + tid;
    b_row[i] = c >> 3;
    b_dch[i] = (c & 7) ^ (b_row[i] & 7);
  }

#define GSTAGE64(buf, kt_)                                                     \
  do {                                                                         \
    int k0_ = (kt_) * 64;                                                      \
    _Pragma("unroll")                                                          \
    for (int i = 0; i < 2; i++)                                                \
      gload_lds16(A + (size_t)(m0 + a_row[i]) * K + k0_ + a_dch[i] * 8,        \
                  Asb + ((buf) * 4096 + (i * 256 + wave * 64) * 8));           \
    _Pragma("unroll")                                                          \
    for (int i = 0; i < 4; i++)                                                \
      gload_lds16(Bt + (size_t)(n0 + b_row[i]) * K + k0_ + b_dch[i] * 8,       \
                  Bsb + ((buf) * 8192 + (i * 256 + wave * 64) * 8));           \
  } while (0)

  GSTAGE64(0, 0);
  __syncthreads();

  for (int kt = 0; kt < nk; kt++) {
    int cur = kt & 1;
    if (kt + 1 < nk) GSTAGE64(cur ^ 1, kt + 1);
#pragma unroll
    for (int kk = 0; kk < 2; kk++) {
      bf16x8 af[4], bfr[2];
#pragma unroll
      for (int mt = 0; mt < 4; mt++) {
        int row = mt * 16 + lr;
        int sl = (kk * 4 + hi) ^ (row & 7);
        af[mt] = *(const bf16x8*)(Asb + cur * 4096 + row * 64 + sl * 8);
      }
#pragma unroll
      for (int nt = 0; nt < 2; nt++) {
        int row = nbase + nt * 32 + lr;
        int sl = (kk * 4 + hi) ^ (row & 7);
        bfr[nt] = *(const bf16x8*)(Bsb + cur * 8192 + row * 64 + sl * 8);
      }
      __builtin_amdgcn_s_setprio(1);
#pragma unroll
      for (int mt = 0; mt < 4; mt++)
#pragma unroll
        for (int nt = 0; nt < 2; nt++) {
          if (EPI == 3) acc[mt][nt] = mfma16(bfr[nt], af[mt], acc[mt][nt]);
          else          acc[mt][nt] = mfma16(af[mt], bfr[nt], acc[mt][nt]);
        }
      __builtin_amdgcn_s_setprio(0);
    }
    __syncthreads();
  }
#undef GSTAGE64

  if (EPI == 1) {
#pragma unroll
    for (int mt = 0; mt < 4; mt++)
#pragma unroll
      for (int r = 0; r < 4; r++) {
        int grow = m0 + mt * 16 + 4 * hi + r;
        int s = grow & (S_ - 1);
        int d = (wave & 1) * 16 + lr;
        int gcol = n0 + nbase + lr;
        float2 cs = tab[s * 32 + d];
        float x1 = acc[mt][0][r], x2 = acc[mt][1][r];
        ((bf16*)Cout)[(size_t)grow * N + gcol]      = (bf16)(x1 * cs.x - x2 * cs.y);
        ((bf16*)Cout)[(size_t)grow * N + gcol + 32] = (bf16)(x2 * cs.x + x1 * cs.y);
      }
  } else {
    int b = m0 >> 11;
#pragma unroll
    for (int mt = 0; mt < 4; mt++)
#pragma unroll
      for (int nt = 0; nt < 2; nt++)
#pragma unroll
        for (int r = 0; r < 4; r++) {
          int n = n0 + nbase + nt * 32 + 4 * hi + r;
          int m = m0 + mt * 16 + lr;
          ((bf16*)Cout)[((size_t)(b * KVD_ + n)) * S_ + (m & (S_ - 1))] =
              (bf16)acc[mt][nt][r];
        }
  }
}

__global__ __launch_bounds__(256) void k_gemm_kv(const bf16* __restrict__ A0,
                                                 const bf16* __restrict__ A1,
                                                 const bf16* __restrict__ B0,
                                                 const bf16* __restrict__ B1,
                                                 bf16* __restrict__ Kh,
                                                 bf16* __restrict__ Vt,
                                                 const float2* __restrict__ tab) {
  __shared__ alignas(16) bf16 As[2][64 * 64];
  __shared__ alignas(16) bf16 Bs[2][128 * 64];
  if (blockIdx.z == 0) gemm_body64<1>(&As[0][0], &Bs[0][0], A0, B0, Kh, tab);
  else                 gemm_body64<3>(&As[0][0], &Bs[0][0], A1, B1, Vt, nullptr);
}

// ---------------- Flash attention v4 (unchanged — control) ----------------
__global__ __launch_bounds__(512, 4) void k_attn(const bf16* __restrict__ Qh,
                                                 const bf16* __restrict__ Kh,
                                                 const bf16* __restrict__ Vt,
                                                 bf16* __restrict__ ctx) {
  __shared__ alignas(16) bf16 Ks[2][64 * 64];
  __shared__ alignas(16) bf16 Vs[2][64 * 64];
  int tid = threadIdx.x;
  int wave = tid >> 6, lane = tid & 63, hi2 = lane >> 5, l31 = lane & 31;
  int qt = blockIdx.x, h = blockIdx.y, b = blockIdx.z;
  int kv = h & 7;
  int q0 = qt * 256 + wave * 32;

  bf16x8 qf[4];
  {
    const float QSC = 0.125f * LOG2E;
    const bf16* qp = Qh + (size_t)(b * S_ + q0 + l31) * D_ + h * HD_ + hi2 * 8;
#pragma unroll
    for (int df = 0; df < 4; df++) {
      bf16x8 v = *(const bf16x8*)(qp + 16 * df);
#pragma unroll
      for (int j = 0; j < 8; j++) v[j] = (bf16)((float)v[j] * QSC);
      qf[df] = v;
    }
  }

  f32x16 o0, o1, accl;
#pragma unroll
  for (int i = 0; i < 16; i++) { o0[i] = 0.f; o1[i] = 0.f; accl[i] = 0.f; }
  bf16x8 ones;
#pragma unroll
  for (int j = 0; j < 8; j++) ones[j] = (bf16)1.0f;

  const bf16* Kg = Kh + (size_t)(b * S_) * KVD_ + kv * HD_;
  const bf16* Vg = Vt + (size_t)(b * KVH_ + kv) * HD_ * S_;

  int c_row = tid >> 3, c_slot = tid & 7;
  int c_dch = c_slot ^ (c_row & 7);

#define STAGE(buf, kt_)                                                        \
  do {                                                                         \
    gload_lds16(Kg + (size_t)((kt_) * 64 + c_row) * KVD_ + c_dch * 8,          \
                &Ks[buf][tid * 8]);                                            \
    gload_lds16(Vg + (size_t)c_row * S_ + (kt_) * 64 + c_dch * 8,              \
                &Vs[buf][tid * 8]);                                            \
  } while (0)

  STAGE(0, 0);
  __syncthreads();

  const int NT = S_ / 64;
  for (int kt = 0; kt < NT; kt++) {
    int cur = kt & 1;
    if (kt + 1 < NT) STAGE(cur ^ 1, kt + 1);

    const bf16* Kb = &Ks[cur][0];
    const bf16* Vb = &Vs[cur][0];

    f32x16 s0, s1;
#pragma unroll
    for (int i = 0; i < 16; i++) { s0[i] = 0.f; s1[i] = 0.f; }
    __builtin_amdgcn_s_setprio(1);
#pragma unroll
    for (int df = 0; df < 4; df++) {
      int ch = hi2 + 2 * df;
      int sl = (ch ^ (l31 & 7)) << 3;
      bf16x8 k0 = *(const bf16x8*)(Kb + l31 * 64 + sl);
      bf16x8 k1 = *(const bf16x8*)(Kb + (l31 + 32) * 64 + sl);
      s0 = mfma32(k0, qf[df], s0);
      s1 = mfma32(k1, qf[df], s1);
    }
    __builtin_amdgcn_s_setprio(0);

#pragma unroll
    for (int i = 0; i < 16; i++) s0[i] = __builtin_amdgcn_exp2f(s0[i]);
#pragma unroll
    for (int i = 0; i < 16; i++) s1[i] = __builtin_amdgcn_exp2f(s1[i]);

    unsigned Rk[2][4][2];
#pragma unroll
    for (int m = 0; m < 4; m++)
#pragma unroll
      for (int w = 0; w < 2; w++) {
        Rk[0][m][w] = pack_bf16(s0[4*m + 2*w], s0[4*m + 2*w + 1]);
        Rk[1][m][w] = pack_bf16(s1[4*m + 2*w], s1[4*m + 2*w + 1]);
      }
#pragma unroll
    for (int kf = 0; kf < 2; kf++)
#pragma unroll
      for (int kp = 0; kp < 2; kp++)
#pragma unroll
        for (int w = 0; w < 2; w++)
          asm volatile("v_permlane32_swap_b32 %0, %1"
                       : "+v"(Rk[kf][2*kp][w]), "+v"(Rk[kf][2*kp+1][w]));
    bf16x8 pf[4];
#pragma unroll
    for (int kfr = 0; kfr < 4; kfr++) {
      int kf = kfr >> 1, k2 = (kfr & 1) * 2;
      union { unsigned d[4]; bf16x8 v; } u;
      u.d[0] = Rk[kf][k2][0];     u.d[1] = Rk[kf][k2][1];
      u.d[2] = Rk[kf][k2 + 1][0]; u.d[3] = Rk[kf][k2 + 1][1];
      pf[kfr] = u.v;
    }

    __builtin_amdgcn_s_setprio(1);
#pragma unroll
    for (int kfr = 0; kfr < 4; kfr++) {
      int ch = hi2 + 2 * kfr;
      int sl = (ch ^ (l31 & 7)) << 3;
      bf16x8 v0 = *(const bf16x8*)(Vb + l31 * 64 + sl);
      bf16x8 v1 = *(const bf16x8*)(Vb + (l31 + 32) * 64 + sl);
      o0 = mfma32(pf[kfr], v0, o0);
      o1 = mfma32(pf[kfr], v1, o1);
      accl = mfma32(pf[kfr], ones, accl);
    }
    __builtin_amdgcn_s_setprio(0);
    __syncthreads();
  }
#undef STAGE

#pragma unroll
  for (int r = 0; r < 16; r++) {
    int rowq = (r & 3) + 8 * (r >> 2) + 4 * hi2;
    float inv = 1.f / accl[r];
    size_t base = (size_t)(b * S_ + q0 + rowq) * D_ + h * HD_;
    ctx[base + l31]      = (bf16)(o0[r] * inv);
    ctx[base + l31 + 32] = (bf16)(o1[r] * inv);
  }
}

// ---------------- host ----------------
extern "C" void kernel_launch(void* const* d_in, const int* in_sizes, int n_in,
                              void* d_out, int out_size, void* d_ws, size_t ws_size,
                              hipStream_t stream) {
  const float* q  = (const float*)d_in[0];
  const float* k  = (const float*)d_in[1];
  const float* v  = (const float*)d_in[2];
  const float* Wq = (const float*)d_in[4];
  const float* Wk = (const float*)d_in[5];
  const float* Wv = (const float*)d_in[6];
  const float* Wo = (const float*)d_in[7];
  const float* bo = (const float*)d_in[8];

  char* ws = (char*)d_ws;
  bf16*   A0  = (bf16*)(ws + 0);           // 16.78 MB: q-act, then k-act
  bf16*   A1  = (bf16*)(ws + 16777216);    // 16.78 MB: v-act, then ctx
  bf16*   Wt  = (bf16*)(ws + 33554432);    //  8.39 MB: WqT/WoT (WkT,WvT packed)
  bf16*   Qh  = (bf16*)(ws + 41943040);    // 16.78 MB
  bf16*   Kh  = (bf16*)(ws + 58720256);    //  4.19 MB
  bf16*   Vt  = (bf16*)(ws + 62914560);    //  4.19 MB  [B][KVD][S]
  float2* tab = (float2*)(ws + 67108864);  //  0.52 MB  (end 67,633,152)
  bf16*   WtK = Wt;
  bf16*   WtV = (bf16*)(ws + 33554432 + 2097152);
  bf16*   ctx = A1;

  const int n4 = NROW_ * D_ / 4;

  k_ropetab<<<(S_ * 32) / 256, 256, 0, stream>>>(tab);
  k_convert<<<n4 / 256, 256, 0, stream>>>(q, A0, n4);
  k_transpose_w<<<dim3(D_/32, D_/32), dim3(32, 8), 0, stream>>>(Wq, Wt, D_, D_);
  k_gemm_q<<<dim3(D_/256, NROW_/128), 256, 0, stream>>>(A0, Wt, Qh, tab);
  k_convert2<<<dim3(n4 / 256, 1, 2), 256, 0, stream>>>(k, v, A0, A1, n4);
  k_transpose_w2<<<dim3(KVD_/32, D_/32, 2), dim3(32, 8), 0, stream>>>(Wk, Wv, WtK, WtV);
  k_gemm_kv<<<dim3(KVD_/128, NROW_/64, 2), 256, 0, stream>>>(A0, A1, WtK, WtV, Kh, Vt, tab);
  k_attn<<<dim3(S_/256, QH_, B_), 512, 0, stream>>>(Qh, Kh, Vt, ctx);
  k_transpose_w<<<dim3(D_/32, D_/32), dim3(32, 8), 0, stream>>>(Wo, Wt, D_, D_);
  k_gemm_o<<<dim3(D_/256, NROW_/128), 256, 0, stream>>>(ctx, Wt, (float*)d_out, bo);
}

// Round 13
// 244.122 us; speedup vs baseline: 1.2603x; 1.2603x over previous
//
#include <hip/hip_runtime.h>
#include <math.h>

#define D_    2048
#define QH_   32
#define KVH_  8
#define HD_   64
#define B_    2
#define S_    2048
#define NROW_ (B_*S_)     // 4096
#define KVD_  (KVH_*HD_)  // 512
#define LOG2E 1.44269504f

typedef __bf16 bf16;
typedef __bf16 bf16x2 __attribute__((ext_vector_type(2)));
typedef __bf16 bf16x4 __attribute__((ext_vector_type(4)));
typedef __bf16 bf16x8 __attribute__((ext_vector_type(8)));
typedef float  f32x4  __attribute__((ext_vector_type(4)));
typedef float  f32x16 __attribute__((ext_vector_type(16)));

__device__ __forceinline__ f32x4 mfma16(bf16x8 a, bf16x8 b, f32x4 c) {
  return __builtin_amdgcn_mfma_f32_16x16x32_bf16(a, b, c, 0, 0, 0);
}
__device__ __forceinline__ f32x16 mfma32(bf16x8 a, bf16x8 b, f32x16 c) {
  return __builtin_amdgcn_mfma_f32_32x32x16_bf16(a, b, c, 0, 0, 0);
}

__device__ __forceinline__ void gload_lds16(const bf16* g, bf16* l) {
  __builtin_amdgcn_global_load_lds(
      (const __attribute__((address_space(1))) void*)g,
      (__attribute__((address_space(3))) void*)l, 16, 0, 0);
}

__device__ __forceinline__ unsigned pack_bf16(float a, float b) {
  union { bf16x2 v; unsigned u; } t;
  t.v[0] = (bf16)a; t.v[1] = (bf16)b;
  return t.u;
}

// ---------------- RoPE cos/sin table: tab[s*32+d] = {cos, sin} ----------------
__global__ void k_ropetab(float2* __restrict__ tab) {
  int idx = blockIdx.x * 256 + threadIdx.x;   // S_*32 = 65536
  int s = idx >> 5, d = idx & 31;
  float invf = exp2f(-(float)d * 0.62286151f);   // theta^(-d/32), log2(1e6)/32
  float ang = (float)s * invf;
  float sn, cs;
  sincosf(ang, &sn, &cs);
  tab[idx] = make_float2(cs, sn);
}

// ---------------- fp32 -> bf16 convert (q only; k/v fused into KV GEMM) ------
__global__ void k_convert(const float* __restrict__ in, bf16* __restrict__ out, int n4) {
  int i = blockIdx.x * 256 + threadIdx.x;
  if (i >= n4) return;
  f32x4 v = ((const f32x4*)in)[i];
  bf16x4 o;
#pragma unroll
  for (int j = 0; j < 4; j++) o[j] = (bf16)v[j];
  ((bf16x4*)out)[i] = o;
}

// ---------- transpose-convert W[K][N] f32 -> Wt[N][K] bf16 ----------
__device__ __forceinline__ void transpose_w_body(const float* W, bf16* Wt, int K, int N) {
  __shared__ float tile[32][33];
  int n0 = blockIdx.x * 32, k0 = blockIdx.y * 32;
  int tx = threadIdx.x, ty = threadIdx.y;  // (32,8)
#pragma unroll
  for (int j = 0; j < 4; j++)
    tile[ty + 8*j][tx] = W[(size_t)(k0 + ty + 8*j) * N + n0 + tx];
  __syncthreads();
#pragma unroll
  for (int j = 0; j < 4; j++)
    Wt[(size_t)(n0 + ty + 8*j) * K + k0 + tx] = (bf16)tile[tx][ty + 8*j];
}

__global__ void k_transpose_w(const float* __restrict__ W, bf16* __restrict__ Wt,
                              int K, int N) {
  transpose_w_body(W, Wt, K, N);
}

__global__ void k_transpose_w2(const float* __restrict__ W0, const float* __restrict__ W1,
                               bf16* __restrict__ T0, bf16* __restrict__ T1) {
  transpose_w_body(blockIdx.z ? W1 : W0, blockIdx.z ? T1 : T0, D_, KVD_);
}

// ---------------- GEMM 128x128 body (round-9 proven), fused epilogues --------
// BK=64, double-buffered, 8-chunk XOR swizzle (slot ^= row&7).
// EPI: 1 = RoPE (bf16 out)  2 = +bias fp32 out
template<int EPI>
__device__ __forceinline__ void gemm_body(bf16* Asb, bf16* Bsb,
                                          const bf16* A, const bf16* Bt, void* Cout,
                                          const float* bias, const float2* tab,
                                          int M, int N, int K) {
  int tid = threadIdx.x;
  int wave = tid >> 6, lane = tid & 63, hi = lane >> 4, lr = lane & 15;
  int wm = wave >> 1, wn = wave & 1;
  int m0 = blockIdx.y * 128, n0 = blockIdx.x * 128;
  f32x4 acc[4][4] = {};
  int nk = K >> 6;   // BK=64

  int s_row[4], s_dch[4];
#pragma unroll
  for (int i = 0; i < 4; i++) {
    int c = i * 256 + tid;
    s_row[i] = c >> 3;
    s_dch[i] = (c & 7) ^ (s_row[i] & 7);
  }

#define GSTAGE(buf, kt_)                                                       \
  do {                                                                         \
    int k0_ = (kt_) * 64;                                                      \
    _Pragma("unroll")                                                          \
    for (int i = 0; i < 4; i++) {                                              \
      gload_lds16(A  + (size_t)(m0 + s_row[i]) * K + k0_ + s_dch[i] * 8,       \
                  Asb + ((buf) * 8192 + (i * 256 + wave * 64) * 8));           \
      gload_lds16(Bt + (size_t)(n0 + s_row[i]) * K + k0_ + s_dch[i] * 8,       \
                  Bsb + ((buf) * 8192 + (i * 256 + wave * 64) * 8));           \
    }                                                                          \
  } while (0)

  GSTAGE(0, 0);
  __syncthreads();

  for (int kt = 0; kt < nk; kt++) {
    int cur = kt & 1;
    if (kt + 1 < nk) GSTAGE(cur ^ 1, kt + 1);
#pragma unroll
    for (int kk = 0; kk < 2; kk++) {
      bf16x8 af[4], bfr[4];
#pragma unroll
      for (int mt = 0; mt < 4; mt++) {
        int row = wm * 64 + mt * 16 + lr;
        int sl = (kk * 4 + hi) ^ (row & 7);
        af[mt] = *(const bf16x8*)(Asb + cur * 8192 + row * 64 + sl * 8);
      }
#pragma unroll
      for (int nt = 0; nt < 4; nt++) {
        int row = wn * 64 + nt * 16 + lr;
        int sl = (kk * 4 + hi) ^ (row & 7);
        bfr[nt] = *(const bf16x8*)(Bsb + cur * 8192 + row * 64 + sl * 8);
      }
      __builtin_amdgcn_s_setprio(1);
#pragma unroll
      for (int mt = 0; mt < 4; mt++)
#pragma unroll
        for (int nt = 0; nt < 4; nt++)
          acc[mt][nt] = mfma16(af[mt], bfr[nt], acc[mt][nt]);
      __builtin_amdgcn_s_setprio(0);
    }
    __syncthreads();
  }
#undef GSTAGE

  if (EPI == 1) {
#pragma unroll
    for (int mt = 0; mt < 4; mt++)
#pragma unroll
      for (int r = 0; r < 4; r++) {
        int grow = m0 + wm * 64 + mt * 16 + 4 * hi + r;
        int s = grow & (S_ - 1);
#pragma unroll
        for (int nt = 0; nt < 2; nt++) {
          int gcol = n0 + wn * 64 + nt * 16 + lr;
          float2 cs = tab[s * 32 + nt * 16 + lr];
          float x1 = acc[mt][nt][r], x2 = acc[mt][nt + 2][r];
          ((bf16*)Cout)[(size_t)grow * N + gcol]      = (bf16)(x1 * cs.x - x2 * cs.y);
          ((bf16*)Cout)[(size_t)grow * N + gcol + 32] = (bf16)(x2 * cs.x + x1 * cs.y);
        }
      }
  } else {
#pragma unroll
    for (int mt = 0; mt < 4; mt++)
#pragma unroll
      for (int nt = 0; nt < 4; nt++)
#pragma unroll
        for (int r = 0; r < 4; r++) {
          int grow = m0 + wm * 64 + mt * 16 + 4 * hi + r;
          int gcol = n0 + wn * 64 + nt * 16 + lr;
          ((float*)Cout)[(size_t)grow * N + gcol] = acc[mt][nt][r] + bias[gcol];
        }
  }
}

__global__ __launch_bounds__(256) void k_gemm_q(const bf16* __restrict__ A,
                                                const bf16* __restrict__ Bt,
                                                bf16* __restrict__ C,
                                                const float2* __restrict__ tab) {
  __shared__ alignas(16) bf16 As[2][128 * 64];
  __shared__ alignas(16) bf16 Bs[2][128 * 64];
  gemm_body<1>(&As[0][0], &Bs[0][0], A, Bt, C, nullptr, tab, NROW_, D_, D_);
}

__global__ __launch_bounds__(256) void k_gemm_o(const bf16* __restrict__ A,
                                                const bf16* __restrict__ Bt,
                                                float* __restrict__ C,
                                                const float* __restrict__ bias) {
  __shared__ alignas(16) bf16 As[2][128 * 64];
  __shared__ alignas(16) bf16 Bs[2][128 * 64];
  gemm_body<2>(&As[0][0], &Bs[0][0], A, Bt, C, bias, nullptr, NROW_, D_, D_);
}

// ---------------- KV GEMM: 64x128 tile, fused fp32->bf16 A-staging -----------
// A is the ORIGINAL fp32 activation (k or v): reg-staged (f32x4 x2 -> cvt ->
// ds_write_b128) into the same [row][slot] layout/swizzle gload_lds produced;
// B (weights, bf16) stays gload_lds. T14 split: A-loads issued before
// compute(t), ds_write after -> HBM latency hides under MFMA phase.
// EPI: 1 = RoPE K out   3 = transposed V store (swapped mfma operands)
template<int EPI>
__device__ __forceinline__ void gemm_body64(bf16* Asb, bf16* Bsb,
                                            const float* Af, const bf16* Bt, void* Cout,
                                            const float2* tab) {
  const int K = D_, N = KVD_;
  int tid = threadIdx.x;
  int wave = tid >> 6, lane = tid & 63, hi = lane >> 4, lr = lane & 15;
  int m0 = blockIdx.y * 64, n0 = blockIdx.x * 128;
  int nbase = (wave >> 1) * 64 + (wave & 1) * 16;   // + nt*32
  f32x4 acc[4][2] = {};
  const int nk = K >> 6;

  // A: 64x64 tile = 512 chunks -> 2/thread; B: 128x64 = 1024 -> 4/thread
  int a_row[2], a_dch[2], b_row[4], b_dch[4];
#pragma unroll
  for (int i = 0; i < 2; i++) {
    int c = i * 256 + tid;
    a_row[i] = c >> 3;
    a_dch[i] = (c & 7) ^ (a_row[i] & 7);
  }
#pragma unroll
  for (int i = 0; i < 4; i++) {
    int c = i * 256 + tid;
    b_row[i] = c >> 3;
    b_dch[i] = (c & 7) ^ (b_row[i] & 7);
  }

  f32x4 areg[2][2];   // [chunk][half] held across compute

#define A_LOAD(kt_)                                                            \
  do {                                                                         \
    int k0_ = (kt_) * 64;                                                      \
    _Pragma("unroll")                                                          \
    for (int i = 0; i < 2; i++) {                                              \
      const float* p = Af + (size_t)(m0 + a_row[i]) * K + k0_ + a_dch[i] * 8;  \
      areg[i][0] = *(const f32x4*)p;                                           \
      areg[i][1] = *(const f32x4*)(p + 4);                                     \
    }                                                                          \
  } while (0)

#define A_WRITE(buf)                                                           \
  do {                                                                         \
    _Pragma("unroll")                                                          \
    for (int i = 0; i < 2; i++) {                                              \
      bf16x8 v;                                                                \
      _Pragma("unroll")                                                        \
      for (int j = 0; j < 4; j++) {                                            \
        v[j]     = (bf16)areg[i][0][j];                                        \
        v[4 + j] = (bf16)areg[i][1][j];                                        \
      }                                                                        \
      *(bf16x8*)(Asb + (buf) * 4096 + (i * 256 + tid) * 8) = v;                \
    }                                                                          \
  } while (0)

#define GSTAGE_B(buf, kt_)                                                     \
  do {                                                                         \
    int k0_ = (kt_) * 64;                                                      \
    _Pragma("unroll")                                                          \
    for (int i = 0; i < 4; i++)                                                \
      gload_lds16(Bt + (size_t)(n0 + b_row[i]) * K + k0_ + b_dch[i] * 8,       \
                  Bsb + ((buf) * 8192 + (i * 256 + wave * 64) * 8));           \
  } while (0)

  A_LOAD(0);
  GSTAGE_B(0, 0);
  A_WRITE(0);
  __syncthreads();

  for (int kt = 0; kt < nk; kt++) {
    int cur = kt & 1;
    if (kt + 1 < nk) {
      A_LOAD(kt + 1);          // regs, in flight across compute
      GSTAGE_B(cur ^ 1, kt + 1);
    }
#pragma unroll
    for (int kk = 0; kk < 2; kk++) {
      bf16x8 af[4], bfr[2];
#pragma unroll
      for (int mt = 0; mt < 4; mt++) {
        int row = mt * 16 + lr;
        int sl = (kk * 4 + hi) ^ (row & 7);
        af[mt] = *(const bf16x8*)(Asb + cur * 4096 + row * 64 + sl * 8);
      }
#pragma unroll
      for (int nt = 0; nt < 2; nt++) {
        int row = nbase + nt * 32 + lr;
        int sl = (kk * 4 + hi) ^ (row & 7);
        bfr[nt] = *(const bf16x8*)(Bsb + cur * 8192 + row * 64 + sl * 8);
      }
      __builtin_amdgcn_s_setprio(1);
#pragma unroll
      for (int mt = 0; mt < 4; mt++)
#pragma unroll
        for (int nt = 0; nt < 2; nt++) {
          if (EPI == 3) acc[mt][nt] = mfma16(bfr[nt], af[mt], acc[mt][nt]);
          else          acc[mt][nt] = mfma16(af[mt], bfr[nt], acc[mt][nt]);
        }
      __builtin_amdgcn_s_setprio(0);
    }
    if (kt + 1 < nk) A_WRITE(cur ^ 1);   // into the buffer not being read
    __syncthreads();
  }
#undef A_LOAD
#undef A_WRITE
#undef GSTAGE_B

  if (EPI == 1) {
    // rope pair: frag nt=0 holds d=(wave&1)*16+lr (<32), nt=1 holds d+32
#pragma unroll
    for (int mt = 0; mt < 4; mt++)
#pragma unroll
      for (int r = 0; r < 4; r++) {
        int grow = m0 + mt * 16 + 4 * hi + r;
        int s = grow & (S_ - 1);
        int d = (wave & 1) * 16 + lr;
        int gcol = n0 + nbase + lr;
        float2 cs = tab[s * 32 + d];
        float x1 = acc[mt][0][r], x2 = acc[mt][1][r];
        ((bf16*)Cout)[(size_t)grow * N + gcol]      = (bf16)(x1 * cs.x - x2 * cs.y);
        ((bf16*)Cout)[(size_t)grow * N + gcol + 32] = (bf16)(x2 * cs.x + x1 * cs.y);
      }
  } else {
    // transposed store: D-row(4hi+r) = n side (bfr), D-col(lr) = m side (af)
    int b = m0 >> 11;
#pragma unroll
    for (int mt = 0; mt < 4; mt++)
#pragma unroll
      for (int nt = 0; nt < 2; nt++)
#pragma unroll
        for (int r = 0; r < 4; r++) {
          int n = n0 + nbase + nt * 32 + 4 * hi + r;
          int m = m0 + mt * 16 + lr;
          ((bf16*)Cout)[((size_t)(b * KVD_ + n)) * S_ + (m & (S_ - 1))] =
              (bf16)acc[mt][nt][r];
        }
  }
}

__global__ __launch_bounds__(256) void k_gemm_kv(const float* __restrict__ kf,
                                                 const float* __restrict__ vf,
                                                 const bf16* __restrict__ B0,
                                                 const bf16* __restrict__ B1,
                                                 bf16* __restrict__ Kh,
                                                 bf16* __restrict__ Vt,
                                                 const float2* __restrict__ tab) {
  __shared__ alignas(16) bf16 As[2][64 * 64];
  __shared__ alignas(16) bf16 Bs[2][128 * 64];
  if (blockIdx.z == 0) gemm_body64<1>(&As[0][0], &Bs[0][0], kf, B0, Kh, tab);
  else                 gemm_body64<3>(&As[0][0], &Bs[0][0], vf, B1, Vt, nullptr);
}

// ---------------- Flash attention v4 (unchanged — control) ----------------
__global__ __launch_bounds__(512, 4) void k_attn(const bf16* __restrict__ Qh,
                                                 const bf16* __restrict__ Kh,
                                                 const bf16* __restrict__ Vt,
                                                 bf16* __restrict__ ctx) {
  __shared__ alignas(16) bf16 Ks[2][64 * 64];
  __shared__ alignas(16) bf16 Vs[2][64 * 64];
  int tid = threadIdx.x;
  int wave = tid >> 6, lane = tid & 63, hi2 = lane >> 5, l31 = lane & 31;
  int qt = blockIdx.x, h = blockIdx.y, b = blockIdx.z;
  int kv = h & 7;
  int q0 = qt * 256 + wave * 32;

  bf16x8 qf[4];
  {
    const float QSC = 0.125f * LOG2E;
    const bf16* qp = Qh + (size_t)(b * S_ + q0 + l31) * D_ + h * HD_ + hi2 * 8;
#pragma unroll
    for (int df = 0; df < 4; df++) {
      bf16x8 v = *(const bf16x8*)(qp + 16 * df);
#pragma unroll
      for (int j = 0; j < 8; j++) v[j] = (bf16)((float)v[j] * QSC);
      qf[df] = v;
    }
  }

  f32x16 o0, o1, accl;
#pragma unroll
  for (int i = 0; i < 16; i++) { o0[i] = 0.f; o1[i] = 0.f; accl[i] = 0.f; }
  bf16x8 ones;
#pragma unroll
  for (int j = 0; j < 8; j++) ones[j] = (bf16)1.0f;

  const bf16* Kg = Kh + (size_t)(b * S_) * KVD_ + kv * HD_;
  const bf16* Vg = Vt + (size_t)(b * KVH_ + kv) * HD_ * S_;

  int c_row = tid >> 3, c_slot = tid & 7;
  int c_dch = c_slot ^ (c_row & 7);

#define STAGE(buf, kt_)                                                        \
  do {                                                                         \
    gload_lds16(Kg + (size_t)((kt_) * 64 + c_row) * KVD_ + c_dch * 8,          \
                &Ks[buf][tid * 8]);                                            \
    gload_lds16(Vg + (size_t)c_row * S_ + (kt_) * 64 + c_dch * 8,              \
                &Vs[buf][tid * 8]);                                            \
  } while (0)

  STAGE(0, 0);
  __syncthreads();

  const int NT = S_ / 64;
  for (int kt = 0; kt < NT; kt++) {
    int cur = kt & 1;
    if (kt + 1 < NT) STAGE(cur ^ 1, kt + 1);

    const bf16* Kb = &Ks[cur][0];
    const bf16* Vb = &Vs[cur][0];

    f32x16 s0, s1;
#pragma unroll
    for (int i = 0; i < 16; i++) { s0[i] = 0.f; s1[i] = 0.f; }
    __builtin_amdgcn_s_setprio(1);
#pragma unroll
    for (int df = 0; df < 4; df++) {
      int ch = hi2 + 2 * df;
      int sl = (ch ^ (l31 & 7)) << 3;
      bf16x8 k0 = *(const bf16x8*)(Kb + l31 * 64 + sl);
      bf16x8 k1 = *(const bf16x8*)(Kb + (l31 + 32) * 64 + sl);
      s0 = mfma32(k0, qf[df], s0);
      s1 = mfma32(k1, qf[df], s1);
    }
    __builtin_amdgcn_s_setprio(0);

#pragma unroll
    for (int i = 0; i < 16; i++) s0[i] = __builtin_amdgcn_exp2f(s0[i]);
#pragma unroll
    for (int i = 0; i < 16; i++) s1[i] = __builtin_amdgcn_exp2f(s1[i]);

    unsigned Rk[2][4][2];
#pragma unroll
    for (int m = 0; m < 4; m++)
#pragma unroll
      for (int w = 0; w < 2; w++) {
        Rk[0][m][w] = pack_bf16(s0[4*m + 2*w], s0[4*m + 2*w + 1]);
        Rk[1][m][w] = pack_bf16(s1[4*m + 2*w], s1[4*m + 2*w + 1]);
      }
#pragma unroll
    for (int kf = 0; kf < 2; kf++)
#pragma unroll
      for (int kp = 0; kp < 2; kp++)
#pragma unroll
        for (int w = 0; w < 2; w++)
          asm volatile("v_permlane32_swap_b32 %0, %1"
                       : "+v"(Rk[kf][2*kp][w]), "+v"(Rk[kf][2*kp+1][w]));
    bf16x8 pf[4];
#pragma unroll
    for (int kfr = 0; kfr < 4; kfr++) {
      int kf = kfr >> 1, k2 = (kfr & 1) * 2;
      union { unsigned d[4]; bf16x8 v; } u;
      u.d[0] = Rk[kf][k2][0];     u.d[1] = Rk[kf][k2][1];
      u.d[2] = Rk[kf][k2 + 1][0]; u.d[3] = Rk[kf][k2 + 1][1];
      pf[kfr] = u.v;
    }

    __builtin_amdgcn_s_setprio(1);
#pragma unroll
    for (int kfr = 0; kfr < 4; kfr++) {
      int ch = hi2 + 2 * kfr;
      int sl = (ch ^ (l31 & 7)) << 3;
      bf16x8 v0 = *(const bf16x8*)(Vb + l31 * 64 + sl);
      bf16x8 v1 = *(const bf16x8*)(Vb + (l31 + 32) * 64 + sl);
      o0 = mfma32(pf[kfr], v0, o0);
      o1 = mfma32(pf[kfr], v1, o1);
      accl = mfma32(pf[kfr], ones, accl);
    }
    __builtin_amdgcn_s_setprio(0);
    __syncthreads();
  }
#undef STAGE

#pragma unroll
  for (int r = 0; r < 16; r++) {
    int rowq = (r & 3) + 8 * (r >> 2) + 4 * hi2;
    float inv = 1.f / accl[r];
    size_t base = (size_t)(b * S_ + q0 + rowq) * D_ + h * HD_;
    ctx[base + l31]      = (bf16)(o0[r] * inv);
    ctx[base + l31 + 32] = (bf16)(o1[r] * inv);
  }
}

// ---------------- host ----------------
extern "C" void kernel_launch(void* const* d_in, const int* in_sizes, int n_in,
                              void* d_out, int out_size, void* d_ws, size_t ws_size,
                              hipStream_t stream) {
  const float* q  = (const float*)d_in[0];
  const float* k  = (const float*)d_in[1];
  const float* v  = (const float*)d_in[2];
  const float* Wq = (const float*)d_in[4];
  const float* Wk = (const float*)d_in[5];
  const float* Wv = (const float*)d_in[6];
  const float* Wo = (const float*)d_in[7];
  const float* bo = (const float*)d_in[8];

  char* ws = (char*)d_ws;
  bf16*   A0  = (bf16*)(ws + 0);           // 16.78 MB: q-act
  bf16*   A1  = (bf16*)(ws + 16777216);    // 16.78 MB: ctx
  bf16*   Wt  = (bf16*)(ws + 33554432);    //  8.39 MB: WqT/WoT (WkT,WvT packed)
  bf16*   Qh  = (bf16*)(ws + 41943040);    // 16.78 MB
  bf16*   Kh  = (bf16*)(ws + 58720256);    //  4.19 MB
  bf16*   Vt  = (bf16*)(ws + 62914560);    //  4.19 MB  [B][KVD][S]
  float2* tab = (float2*)(ws + 67108864);  //  0.52 MB  (end 67,633,152)
  bf16*   WtK = Wt;
  bf16*   WtV = (bf16*)(ws + 33554432 + 2097152);
  bf16*   ctx = A1;

  const int n4 = NROW_ * D_ / 4;

  k_ropetab<<<(S_ * 32) / 256, 256, 0, stream>>>(tab);
  k_convert<<<n4 / 256, 256, 0, stream>>>(q, A0, n4);
  k_transpose_w<<<dim3(D_/32, D_/32), dim3(32, 8), 0, stream>>>(Wq, Wt, D_, D_);
  k_gemm_q<<<dim3(D_/128, NROW_/128), 256, 0, stream>>>(A0, Wt, Qh, tab);
  k_transpose_w2<<<dim3(KVD_/32, D_/32, 2), dim3(32, 8), 0, stream>>>(Wk, Wv, WtK, WtV);
  k_gemm_kv<<<dim3(KVD_/128, NROW_/64, 2), 256, 0, stream>>>(k, v, WtK, WtV, Kh, Vt, tab);
  k_attn<<<dim3(S_/256, QH_, B_), 512, 0, stream>>>(Qh, Kh, Vt, ctx);
  k_transpose_w<<<dim3(D_/32, D_/32), dim3(32, 8), 0, stream>>>(Wo, Wt, D_, D_);
  k_gemm_o<<<dim3(D_/128, NROW_/128), 256, 0, stream>>>(ctx, Wt, (float*)d_out, bo);
}

// Round 14
// 240.746 us; speedup vs baseline: 1.2780x; 1.0140x over previous
//
#include <hip/hip_runtime.h>
#include <math.h>

#define D_    2048
#define QH_   32
#define KVH_  8
#define HD_   64
#define B_    2
#define S_    2048
#define NROW_ (B_*S_)     // 4096
#define KVD_  (KVH_*HD_)  // 512
#define LOG2E 1.44269504f

typedef __bf16 bf16;
typedef __bf16 bf16x2 __attribute__((ext_vector_type(2)));
typedef __bf16 bf16x4 __attribute__((ext_vector_type(4)));
typedef __bf16 bf16x8 __attribute__((ext_vector_type(8)));
typedef float  f32x4  __attribute__((ext_vector_type(4)));
typedef float  f32x16 __attribute__((ext_vector_type(16)));

__device__ __forceinline__ f32x4 mfma16(bf16x8 a, bf16x8 b, f32x4 c) {
  return __builtin_amdgcn_mfma_f32_16x16x32_bf16(a, b, c, 0, 0, 0);
}
__device__ __forceinline__ f32x16 mfma32(bf16x8 a, bf16x8 b, f32x16 c) {
  return __builtin_amdgcn_mfma_f32_32x32x16_bf16(a, b, c, 0, 0, 0);
}

__device__ __forceinline__ void gload_lds16(const bf16* g, bf16* l) {
  __builtin_amdgcn_global_load_lds(
      (const __attribute__((address_space(1))) void*)g,
      (__attribute__((address_space(3))) void*)l, 16, 0, 0);
}

__device__ __forceinline__ unsigned pack_bf16(float a, float b) {
  union { bf16x2 v; unsigned u; } t;
  t.v[0] = (bf16)a; t.v[1] = (bf16)b;
  return t.u;
}

// ---------------- RoPE cos/sin table: tab[s*32+d] = {cos, sin} ----------------
__global__ void k_ropetab(float2* __restrict__ tab) {
  int idx = blockIdx.x * 256 + threadIdx.x;   // S_*32 = 65536
  int s = idx >> 5, d = idx & 31;
  float invf = exp2f(-(float)d * 0.62286151f);   // theta^(-d/32), log2(1e6)/32
  float ang = (float)s * invf;
  float sn, cs;
  sincosf(ang, &sn, &cs);
  tab[idx] = make_float2(cs, sn);
}

// ---------- transpose-convert W[K][N] f32 -> Wt[N][K] bf16 ----------
__device__ __forceinline__ void transpose_w_body(const float* W, bf16* Wt, int K, int N) {
  __shared__ float tile[32][33];
  int n0 = blockIdx.x * 32, k0 = blockIdx.y * 32;
  int tx = threadIdx.x, ty = threadIdx.y;  // (32,8)
#pragma unroll
  for (int j = 0; j < 4; j++)
    tile[ty + 8*j][tx] = W[(size_t)(k0 + ty + 8*j) * N + n0 + tx];
  __syncthreads();
#pragma unroll
  for (int j = 0; j < 4; j++)
    Wt[(size_t)(n0 + ty + 8*j) * K + k0 + tx] = (bf16)tile[tx][ty + 8*j];
}

__global__ void k_transpose_w(const float* __restrict__ W, bf16* __restrict__ Wt,
                              int K, int N) {
  transpose_w_body(W, Wt, K, N);
}

__global__ void k_transpose_w2(const float* __restrict__ W0, const float* __restrict__ W1,
                               bf16* __restrict__ T0, bf16* __restrict__ T1) {
  transpose_w_body(blockIdx.z ? W1 : W0, blockIdx.z ? T1 : T0, D_, KVD_);
}

// ---------------- GEMM 128x128 body (bf16 A), fused epilogues --------
// BK=64, double-buffered, 8-chunk XOR swizzle (slot ^= row&7).
// EPI: 2 = +bias fp32 out [O-proj]
template<int EPI>
__device__ __forceinline__ void gemm_body(bf16* Asb, bf16* Bsb,
                                          const bf16* A, const bf16* Bt, void* Cout,
                                          const float* bias, const float2* tab,
                                          int M, int N, int K) {
  int tid = threadIdx.x;
  int wave = tid >> 6, lane = tid & 63, hi = lane >> 4, lr = lane & 15;
  int wm = wave >> 1, wn = wave & 1;
  int m0 = blockIdx.y * 128, n0 = blockIdx.x * 128;
  f32x4 acc[4][4] = {};
  int nk = K >> 6;   // BK=64

  int s_row[4], s_dch[4];
#pragma unroll
  for (int i = 0; i < 4; i++) {
    int c = i * 256 + tid;
    s_row[i] = c >> 3;
    s_dch[i] = (c & 7) ^ (s_row[i] & 7);
  }

#define GSTAGE(buf, kt_)                                                       \
  do {                                                                         \
    int k0_ = (kt_) * 64;                                                      \
    _Pragma("unroll")                                                          \
    for (int i = 0; i < 4; i++) {                                              \
      gload_lds16(A  + (size_t)(m0 + s_row[i]) * K + k0_ + s_dch[i] * 8,       \
                  Asb + ((buf) * 8192 + (i * 256 + wave * 64) * 8));           \
      gload_lds16(Bt + (size_t)(n0 + s_row[i]) * K + k0_ + s_dch[i] * 8,       \
                  Bsb + ((buf) * 8192 + (i * 256 + wave * 64) * 8));           \
    }                                                                          \
  } while (0)

  GSTAGE(0, 0);
  __syncthreads();

  for (int kt = 0; kt < nk; kt++) {
    int cur = kt & 1;
    if (kt + 1 < nk) GSTAGE(cur ^ 1, kt + 1);
#pragma unroll
    for (int kk = 0; kk < 2; kk++) {
      bf16x8 af[4], bfr[4];
#pragma unroll
      for (int mt = 0; mt < 4; mt++) {
        int row = wm * 64 + mt * 16 + lr;
        int sl = (kk * 4 + hi) ^ (row & 7);
        af[mt] = *(const bf16x8*)(Asb + cur * 8192 + row * 64 + sl * 8);
      }
#pragma unroll
      for (int nt = 0; nt < 4; nt++) {
        int row = wn * 64 + nt * 16 + lr;
        int sl = (kk * 4 + hi) ^ (row & 7);
        bfr[nt] = *(const bf16x8*)(Bsb + cur * 8192 + row * 64 + sl * 8);
      }
      __builtin_amdgcn_s_setprio(1);
#pragma unroll
      for (int mt = 0; mt < 4; mt++)
#pragma unroll
        for (int nt = 0; nt < 4; nt++)
          acc[mt][nt] = mfma16(af[mt], bfr[nt], acc[mt][nt]);
      __builtin_amdgcn_s_setprio(0);
    }
    __syncthreads();
  }
#undef GSTAGE

#pragma unroll
  for (int mt = 0; mt < 4; mt++)
#pragma unroll
    for (int nt = 0; nt < 4; nt++)
#pragma unroll
      for (int r = 0; r < 4; r++) {
        int grow = m0 + wm * 64 + mt * 16 + 4 * hi + r;
        int gcol = n0 + wn * 64 + nt * 16 + lr;
        ((float*)Cout)[(size_t)grow * N + gcol] = acc[mt][nt][r] + bias[gcol];
      }
}

// ---------------- Q-proj GEMM: fp32 A reg-staged (fused convert) + RoPE ------
// A tile 128x64 = 1024 chunks -> 4/thread; same layout/swizzle as gload path.
__global__ __launch_bounds__(256) void k_gemm_q(const float* __restrict__ Af,
                                                const bf16* __restrict__ Bt,
                                                bf16* __restrict__ C,
                                                const float2* __restrict__ tab) {
  __shared__ alignas(16) bf16 As[2][128 * 64];
  __shared__ alignas(16) bf16 Bs[2][128 * 64];
  bf16* Asb = &As[0][0];
  bf16* Bsb = &Bs[0][0];
  const int M = NROW_, N = D_, K = D_;
  int tid = threadIdx.x;
  int wave = tid >> 6, lane = tid & 63, hi = lane >> 4, lr = lane & 15;
  int wm = wave >> 1, wn = wave & 1;
  int m0 = blockIdx.y * 128, n0 = blockIdx.x * 128;
  f32x4 acc[4][4] = {};
  const int nk = K >> 6;

  int s_row[4], s_dch[4];
#pragma unroll
  for (int i = 0; i < 4; i++) {
    int c = i * 256 + tid;
    s_row[i] = c >> 3;
    s_dch[i] = (c & 7) ^ (s_row[i] & 7);
  }

  f32x4 areg[4][2];

#define A_LOADQ(kt_)                                                           \
  do {                                                                         \
    int k0_ = (kt_) * 64;                                                      \
    _Pragma("unroll")                                                          \
    for (int i = 0; i < 4; i++) {                                              \
      const float* p = Af + (size_t)(m0 + s_row[i]) * K + k0_ + s_dch[i] * 8;  \
      areg[i][0] = *(const f32x4*)p;                                           \
      areg[i][1] = *(const f32x4*)(p + 4);                                     \
    }                                                                          \
  } while (0)

#define A_WRITEQ(buf)                                                          \
  do {                                                                         \
    _Pragma("unroll")                                                          \
    for (int i = 0; i < 4; i++) {                                              \
      bf16x8 v;                                                                \
      _Pragma("unroll")                                                        \
      for (int j = 0; j < 4; j++) {                                            \
        v[j]     = (bf16)areg[i][0][j];                                        \
        v[4 + j] = (bf16)areg[i][1][j];                                        \
      }                                                                        \
      *(bf16x8*)(Asb + (buf) * 8192 + (i * 256 + tid) * 8) = v;                \
    }                                                                          \
  } while (0)

#define GSTAGE_BQ(buf, kt_)                                                    \
  do {                                                                         \
    int k0_ = (kt_) * 64;                                                      \
    _Pragma("unroll")                                                          \
    for (int i = 0; i < 4; i++)                                                \
      gload_lds16(Bt + (size_t)(n0 + s_row[i]) * K + k0_ + s_dch[i] * 8,       \
                  Bsb + ((buf) * 8192 + (i * 256 + wave * 64) * 8));           \
  } while (0)

  A_LOADQ(0);
  GSTAGE_BQ(0, 0);
  A_WRITEQ(0);
  __syncthreads();

  for (int kt = 0; kt < nk; kt++) {
    int cur = kt & 1;
    if (kt + 1 < nk) {
      A_LOADQ(kt + 1);
      GSTAGE_BQ(cur ^ 1, kt + 1);
    }
#pragma unroll
    for (int kk = 0; kk < 2; kk++) {
      bf16x8 af[4], bfr[4];
#pragma unroll
      for (int mt = 0; mt < 4; mt++) {
        int row = wm * 64 + mt * 16 + lr;
        int sl = (kk * 4 + hi) ^ (row & 7);
        af[mt] = *(const bf16x8*)(Asb + cur * 8192 + row * 64 + sl * 8);
      }
#pragma unroll
      for (int nt = 0; nt < 4; nt++) {
        int row = wn * 64 + nt * 16 + lr;
        int sl = (kk * 4 + hi) ^ (row & 7);
        bfr[nt] = *(const bf16x8*)(Bsb + cur * 8192 + row * 64 + sl * 8);
      }
      __builtin_amdgcn_s_setprio(1);
#pragma unroll
      for (int mt = 0; mt < 4; mt++)
#pragma unroll
        for (int nt = 0; nt < 4; nt++)
          acc[mt][nt] = mfma16(af[mt], bfr[nt], acc[mt][nt]);
      __builtin_amdgcn_s_setprio(0);
    }
    if (kt + 1 < nk) A_WRITEQ(cur ^ 1);
    __syncthreads();
  }
#undef A_LOADQ
#undef A_WRITEQ
#undef GSTAGE_BQ

  // RoPE epilogue: pair (d, d+32) = (nt, nt+2); d = nt*16+lr < 32
#pragma unroll
  for (int mt = 0; mt < 4; mt++)
#pragma unroll
    for (int r = 0; r < 4; r++) {
      int grow = m0 + wm * 64 + mt * 16 + 4 * hi + r;
      int s = grow & (S_ - 1);
#pragma unroll
      for (int nt = 0; nt < 2; nt++) {
        int gcol = n0 + wn * 64 + nt * 16 + lr;
        float2 cs = tab[s * 32 + nt * 16 + lr];
        float x1 = acc[mt][nt][r], x2 = acc[mt][nt + 2][r];
        C[(size_t)grow * N + gcol]      = (bf16)(x1 * cs.x - x2 * cs.y);
        C[(size_t)grow * N + gcol + 32] = (bf16)(x2 * cs.x + x1 * cs.y);
      }
    }
}

__global__ __launch_bounds__(256) void k_gemm_o(const bf16* __restrict__ A,
                                                const bf16* __restrict__ Bt,
                                                float* __restrict__ C,
                                                const float* __restrict__ bias) {
  __shared__ alignas(16) bf16 As[2][128 * 64];
  __shared__ alignas(16) bf16 Bs[2][128 * 64];
  gemm_body<2>(&As[0][0], &Bs[0][0], A, Bt, C, bias, nullptr, NROW_, D_, D_);
}

// ---------------- KV GEMM: 64x128 tile, fused fp32->bf16 A-staging (r13) -----
template<int EPI>
__device__ __forceinline__ void gemm_body64(bf16* Asb, bf16* Bsb,
                                            const float* Af, const bf16* Bt, void* Cout,
                                            const float2* tab) {
  const int K = D_, N = KVD_;
  int tid = threadIdx.x;
  int wave = tid >> 6, lane = tid & 63, hi = lane >> 4, lr = lane & 15;
  int m0 = blockIdx.y * 64, n0 = blockIdx.x * 128;
  int nbase = (wave >> 1) * 64 + (wave & 1) * 16;   // + nt*32
  f32x4 acc[4][2] = {};
  const int nk = K >> 6;

  int a_row[2], a_dch[2], b_row[4], b_dch[4];
#pragma unroll
  for (int i = 0; i < 2; i++) {
    int c = i * 256 + tid;
    a_row[i] = c >> 3;
    a_dch[i] = (c & 7) ^ (a_row[i] & 7);
  }
#pragma unroll
  for (int i = 0; i < 4; i++) {
    int c = i * 256 + tid;
    b_row[i] = c >> 3;
    b_dch[i] = (c & 7) ^ (b_row[i] & 7);
  }

  f32x4 areg[2][2];

#define A_LOAD(kt_)                                                            \
  do {                                                                         \
    int k0_ = (kt_) * 64;                                                      \
    _Pragma("unroll")                                                          \
    for (int i = 0; i < 2; i++) {                                              \
      const float* p = Af + (size_t)(m0 + a_row[i]) * K + k0_ + a_dch[i] * 8;  \
      areg[i][0] = *(const f32x4*)p;                                           \
      areg[i][1] = *(const f32x4*)(p + 4);                                     \
    }                                                                          \
  } while (0)

#define A_WRITE(buf)                                                           \
  do {                                                                         \
    _Pragma("unroll")                                                          \
    for (int i = 0; i < 2; i++) {                                              \
      bf16x8 v;                                                                \
      _Pragma("unroll")                                                        \
      for (int j = 0; j < 4; j++) {                                            \
        v[j]     = (bf16)areg[i][0][j];                                        \
        v[4 + j] = (bf16)areg[i][1][j];                                        \
      }                                                                        \
      *(bf16x8*)(Asb + (buf) * 4096 + (i * 256 + tid) * 8) = v;                \
    }                                                                          \
  } while (0)

#define GSTAGE_B(buf, kt_)                                                     \
  do {                                                                         \
    int k0_ = (kt_) * 64;                                                      \
    _Pragma("unroll")                                                          \
    for (int i = 0; i < 4; i++)                                                \
      gload_lds16(Bt + (size_t)(n0 + b_row[i]) * K + k0_ + b_dch[i] * 8,       \
                  Bsb + ((buf) * 8192 + (i * 256 + wave * 64) * 8));           \
  } while (0)

  A_LOAD(0);
  GSTAGE_B(0, 0);
  A_WRITE(0);
  __syncthreads();

  for (int kt = 0; kt < nk; kt++) {
    int cur = kt & 1;
    if (kt + 1 < nk) {
      A_LOAD(kt + 1);
      GSTAGE_B(cur ^ 1, kt + 1);
    }
#pragma unroll
    for (int kk = 0; kk < 2; kk++) {
      bf16x8 af[4], bfr[2];
#pragma unroll
      for (int mt = 0; mt < 4; mt++) {
        int row = mt * 16 + lr;
        int sl = (kk * 4 + hi) ^ (row & 7);
        af[mt] = *(const bf16x8*)(Asb + cur * 4096 + row * 64 + sl * 8);
      }
#pragma unroll
      for (int nt = 0; nt < 2; nt++) {
        int row = nbase + nt * 32 + lr;
        int sl = (kk * 4 + hi) ^ (row & 7);
        bfr[nt] = *(const bf16x8*)(Bsb + cur * 8192 + row * 64 + sl * 8);
      }
      __builtin_amdgcn_s_setprio(1);
#pragma unroll
      for (int mt = 0; mt < 4; mt++)
#pragma unroll
        for (int nt = 0; nt < 2; nt++) {
          if (EPI == 3) acc[mt][nt] = mfma16(bfr[nt], af[mt], acc[mt][nt]);
          else          acc[mt][nt] = mfma16(af[mt], bfr[nt], acc[mt][nt]);
        }
      __builtin_amdgcn_s_setprio(0);
    }
    if (kt + 1 < nk) A_WRITE(cur ^ 1);
    __syncthreads();
  }
#undef A_LOAD
#undef A_WRITE
#undef GSTAGE_B

  if (EPI == 1) {
#pragma unroll
    for (int mt = 0; mt < 4; mt++)
#pragma unroll
      for (int r = 0; r < 4; r++) {
        int grow = m0 + mt * 16 + 4 * hi + r;
        int s = grow & (S_ - 1);
        int d = (wave & 1) * 16 + lr;
        int gcol = n0 + nbase + lr;
        float2 cs = tab[s * 32 + d];
        float x1 = acc[mt][0][r], x2 = acc[mt][1][r];
        ((bf16*)Cout)[(size_t)grow * N + gcol]      = (bf16)(x1 * cs.x - x2 * cs.y);
        ((bf16*)Cout)[(size_t)grow * N + gcol + 32] = (bf16)(x2 * cs.x + x1 * cs.y);
      }
  } else {
    int b = m0 >> 11;
#pragma unroll
    for (int mt = 0; mt < 4; mt++)
#pragma unroll
      for (int nt = 0; nt < 2; nt++)
#pragma unroll
        for (int r = 0; r < 4; r++) {
          int n = n0 + nbase + nt * 32 + 4 * hi + r;
          int m = m0 + mt * 16 + lr;
          ((bf16*)Cout)[((size_t)(b * KVD_ + n)) * S_ + (m & (S_ - 1))] =
              (bf16)acc[mt][nt][r];
        }
  }
}

__global__ __launch_bounds__(256) void k_gemm_kv(const float* __restrict__ kf,
                                                 const float* __restrict__ vf,
                                                 const bf16* __restrict__ B0,
                                                 const bf16* __restrict__ B1,
                                                 bf16* __restrict__ Kh,
                                                 bf16* __restrict__ Vt,
                                                 const float2* __restrict__ tab) {
  __shared__ alignas(16) bf16 As[2][64 * 64];
  __shared__ alignas(16) bf16 Bs[2][128 * 64];
  if (blockIdx.z == 0) gemm_body64<1>(&As[0][0], &Bs[0][0], kf, B0, Kh, tab);
  else                 gemm_body64<3>(&As[0][0], &Bs[0][0], vf, B1, Vt, nullptr);
}

// ---------------- Flash attention v6: v4 minus accl-MFMA (scalar l) ----------
__global__ __launch_bounds__(512, 4) void k_attn(const bf16* __restrict__ Qh,
                                                 const bf16* __restrict__ Kh,
                                                 const bf16* __restrict__ Vt,
                                                 bf16* __restrict__ ctx) {
  __shared__ alignas(16) bf16 Ks[2][64 * 64];
  __shared__ alignas(16) bf16 Vs[2][64 * 64];
  int tid = threadIdx.x;
  int wave = tid >> 6, lane = tid & 63, hi2 = lane >> 5, l31 = lane & 31;
  int qt = blockIdx.x, h = blockIdx.y, b = blockIdx.z;
  int kv = h & 7;
  int q0 = qt * 256 + wave * 32;

  bf16x8 qf[4];
  {
    const float QSC = 0.125f * LOG2E;
    const bf16* qp = Qh + (size_t)(b * S_ + q0 + l31) * D_ + h * HD_ + hi2 * 8;
#pragma unroll
    for (int df = 0; df < 4; df++) {
      bf16x8 v = *(const bf16x8*)(qp + 16 * df);
#pragma unroll
      for (int j = 0; j < 8; j++) v[j] = (bf16)((float)v[j] * QSC);
      qf[df] = v;
    }
  }

  float l_run = 0.f;
  f32x16 o0, o1;
#pragma unroll
  for (int i = 0; i < 16; i++) { o0[i] = 0.f; o1[i] = 0.f; }

  const bf16* Kg = Kh + (size_t)(b * S_) * KVD_ + kv * HD_;
  const bf16* Vg = Vt + (size_t)(b * KVH_ + kv) * HD_ * S_;

  int c_row = tid >> 3, c_slot = tid & 7;
  int c_dch = c_slot ^ (c_row & 7);

#define STAGE(buf, kt_)                                                        \
  do {                                                                         \
    gload_lds16(Kg + (size_t)((kt_) * 64 + c_row) * KVD_ + c_dch * 8,          \
                &Ks[buf][tid * 8]);                                            \
    gload_lds16(Vg + (size_t)c_row * S_ + (kt_) * 64 + c_dch * 8,              \
                &Vs[buf][tid * 8]);                                            \
  } while (0)

  STAGE(0, 0);
  __syncthreads();

  const int NT = S_ / 64;
  for (int kt = 0; kt < NT; kt++) {
    int cur = kt & 1;
    if (kt + 1 < NT) STAGE(cur ^ 1, kt + 1);

    const bf16* Kb = &Ks[cur][0];
    const bf16* Vb = &Vs[cur][0];

    f32x16 s0, s1;
#pragma unroll
    for (int i = 0; i < 16; i++) { s0[i] = 0.f; s1[i] = 0.f; }
    __builtin_amdgcn_s_setprio(1);
#pragma unroll
    for (int df = 0; df < 4; df++) {
      int ch = hi2 + 2 * df;
      int sl = (ch ^ (l31 & 7)) << 3;
      bf16x8 k0 = *(const bf16x8*)(Kb + l31 * 64 + sl);
      bf16x8 k1 = *(const bf16x8*)(Kb + (l31 + 32) * 64 + sl);
      s0 = mfma32(k0, qf[df], s0);
      s1 = mfma32(k1, qf[df], s1);
    }
    __builtin_amdgcn_s_setprio(0);

    float rs = 0.f;
#pragma unroll
    for (int i = 0; i < 16; i++) { s0[i] = __builtin_amdgcn_exp2f(s0[i]); rs += s0[i]; }
#pragma unroll
    for (int i = 0; i < 16; i++) { s1[i] = __builtin_amdgcn_exp2f(s1[i]); rs += s1[i]; }
    l_run += rs;

    unsigned Rk[2][4][2];
#pragma unroll
    for (int m = 0; m < 4; m++)
#pragma unroll
      for (int w = 0; w < 2; w++) {
        Rk[0][m][w] = pack_bf16(s0[4*m + 2*w], s0[4*m + 2*w + 1]);
        Rk[1][m][w] = pack_bf16(s1[4*m + 2*w], s1[4*m + 2*w + 1]);
      }
#pragma unroll
    for (int kf = 0; kf < 2; kf++)
#pragma unroll
      for (int kp = 0; kp < 2; kp++)
#pragma unroll
        for (int w = 0; w < 2; w++)
          asm volatile("v_permlane32_swap_b32 %0, %1"
                       : "+v"(Rk[kf][2*kp][w]), "+v"(Rk[kf][2*kp+1][w]));
    bf16x8 pf[4];
#pragma unroll
    for (int kfr = 0; kfr < 4; kfr++) {
      int kf = kfr >> 1, k2 = (kfr & 1) * 2;
      union { unsigned d[4]; bf16x8 v; } u;
      u.d[0] = Rk[kf][k2][0];     u.d[1] = Rk[kf][k2][1];
      u.d[2] = Rk[kf][k2 + 1][0]; u.d[3] = Rk[kf][k2 + 1][1];
      pf[kfr] = u.v;
    }

    __builtin_amdgcn_s_setprio(1);
#pragma unroll
    for (int kfr = 0; kfr < 4; kfr++) {
      int ch = hi2 + 2 * kfr;
      int sl = (ch ^ (l31 & 7)) << 3;
      bf16x8 v0 = *(const bf16x8*)(Vb + l31 * 64 + sl);
      bf16x8 v1 = *(const bf16x8*)(Vb + (l31 + 32) * 64 + sl);
      o0 = mfma32(pf[kfr], v0, o0);
      o1 = mfma32(pf[kfr], v1, o1);
    }
    __builtin_amdgcn_s_setprio(0);
    __syncthreads();
  }
#undef STAGE

  // combine key-halves of l (lane q=l31 holds 32-key partial per hi2)
  float l_full = l_run + __shfl_xor(l_run, 32, 64);
#pragma unroll
  for (int r = 0; r < 16; r++) {
    int rowq = (r & 3) + 8 * (r >> 2) + 4 * hi2;
    float inv = 1.f / __shfl(l_full, rowq, 64);
    size_t base = (size_t)(b * S_ + q0 + rowq) * D_ + h * HD_;
    ctx[base + l31]      = (bf16)(o0[r] * inv);
    ctx[base + l31 + 32] = (bf16)(o1[r] * inv);
  }
}

// ---------------- host ----------------
extern "C" void kernel_launch(void* const* d_in, const int* in_sizes, int n_in,
                              void* d_out, int out_size, void* d_ws, size_t ws_size,
                              hipStream_t stream) {
  const float* q  = (const float*)d_in[0];
  const float* k  = (const float*)d_in[1];
  const float* v  = (const float*)d_in[2];
  const float* Wq = (const float*)d_in[4];
  const float* Wk = (const float*)d_in[5];
  const float* Wv = (const float*)d_in[6];
  const float* Wo = (const float*)d_in[7];
  const float* bo = (const float*)d_in[8];

  char* ws = (char*)d_ws;
  bf16*   A1  = (bf16*)(ws + 16777216);    // 16.78 MB: ctx
  bf16*   Wt  = (bf16*)(ws + 33554432);    //  8.39 MB: WqT/WoT (WkT,WvT packed)
  bf16*   Qh  = (bf16*)(ws + 41943040);    // 16.78 MB
  bf16*   Kh  = (bf16*)(ws + 58720256);    //  4.19 MB
  bf16*   Vt  = (bf16*)(ws + 62914560);    //  4.19 MB  [B][KVD][S]
  float2* tab = (float2*)(ws + 67108864);  //  0.52 MB  (end 67,633,152)
  bf16*   WtK = Wt;
  bf16*   WtV = (bf16*)(ws + 33554432 + 2097152);
  bf16*   ctx = A1;

  k_ropetab<<<(S_ * 32) / 256, 256, 0, stream>>>(tab);
  k_transpose_w<<<dim3(D_/32, D_/32), dim3(32, 8), 0, stream>>>(Wq, Wt, D_, D_);
  k_gemm_q<<<dim3(D_/128, NROW_/128), 256, 0, stream>>>(q, Wt, Qh, tab);
  k_transpose_w2<<<dim3(KVD_/32, D_/32, 2), dim3(32, 8), 0, stream>>>(Wk, Wv, WtK, WtV);
  k_gemm_kv<<<dim3(KVD_/128, NROW_/64, 2), 256, 0, stream>>>(k, v, WtK, WtV, Kh, Vt, tab);
  k_attn<<<dim3(S_/256, QH_, B_), 512, 0, stream>>>(Qh, Kh, Vt, ctx);
  k_transpose_w<<<dim3(D_/32, D_/32), dim3(32, 8), 0, stream>>>(Wo, Wt, D_, D_);
  k_gemm_o<<<dim3(D_/128, NROW_/128), 256, 0, stream>>>(ctx, Wt, (float*)d_out, bo);
}